// Round 1
// baseline (808.303 us; speedup 1.0000x reference)
//
#include <hip/hip_runtime.h>
#include <stdint.h>

// Problem constants: B=8, N=4096, C=768, G=16, D=48
// qkv GEMM: M=32768, N=2304, K=768 ; proj GEMM: M=32768, N=768, K=768

using short8 = __attribute__((__ext_vector_type__(8))) short;
using f32x4  = __attribute__((__ext_vector_type__(4))) float;

typedef const void __attribute__((address_space(1))) gv_t;
typedef void __attribute__((address_space(3))) lv_t;

__device__ __forceinline__ void gll16(const void* g, void* l) {
  __builtin_amdgcn_global_load_lds((gv_t*)g, (lv_t*)l, 16, 0, 0);
}

__device__ __forceinline__ uint16_t f2b(float f) {
  uint32_t x = __float_as_uint(f);
  uint32_t r = (x + 0x7fffu + ((x >> 16) & 1u)) >> 16;  // RNE
  return (uint16_t)r;
}
__device__ __forceinline__ float b2f(uint16_t u) {
  return __uint_as_float(((uint32_t)u) << 16);
}

// ---------------- cast / transpose helpers ----------------

__global__ __launch_bounds__(256) void cast_x_kernel(const float* __restrict__ x,
                                                     uint16_t* __restrict__ xb, int n4) {
  int i = blockIdx.x * 256 + threadIdx.x;
  if (i >= n4) return;
  f32x4 v = ((const f32x4*)x)[i];
  union { uint16_t u[4]; uint64_t q; } o;
  o.u[0] = f2b(v[0]); o.u[1] = f2b(v[1]); o.u[2] = f2b(v[2]); o.u[3] = f2b(v[3]);
  ((uint64_t*)xb)[i] = o.q;
}

// wt[n*K + k] = (bf16) w[k*N + n]
__global__ __launch_bounds__(256) void transpose_cast_kernel(const float* __restrict__ w,
                                                             uint16_t* __restrict__ wt,
                                                             int K, int N) {
  int i = blockIdx.x * 256 + threadIdx.x;
  if (i >= N * K) return;
  int n = i / K, k = i - n * K;
  wt[i] = f2b(w[(size_t)k * N + n]);
}

// ---------------- QKV GEMM (128x128 tile, bf16 MFMA) ----------------
// A [32768][768] bf16, Bt [2304][768] bf16 (w_qkv transposed)
// Epilogue: +bias, q*=1/64, scatter to Q/K/V in [B][G][N][48] layout (bf16)

__global__ __launch_bounds__(256, 2) void gemm_qkv_kernel(
    const uint16_t* __restrict__ A, const uint16_t* __restrict__ Bt,
    const float* __restrict__ bias,
    uint16_t* __restrict__ Qb, uint16_t* __restrict__ Kb, uint16_t* __restrict__ Vb) {
  __shared__ uint16_t As[128 * 32];
  __shared__ uint16_t Bs[128 * 32];
  const int tid = threadIdx.x;
  const int m0 = blockIdx.x * 128;
  const int n0 = blockIdx.y * 128;
  const int lane = tid & 63, wid = tid >> 6;
  const int wr = wid >> 1, wc = wid & 1;
  const int lrow = lane & 15, kb = lane >> 4;

  const int off  = tid * 16;          // staging byte offset within 4KB half
  const int srow = off >> 6;          // 64B (=32 bf16) per LDS row
  const int scol = (off & 63) >> 1;   // element col (multiple of 8)

  f32x4 acc[4][4] = {};

  for (int k0 = 0; k0 < 768; k0 += 32) {
    gll16(A  + (size_t)(m0 + srow)      * 768 + k0 + scol, (char*)As + off);
    gll16(A  + (size_t)(m0 + 64 + srow) * 768 + k0 + scol, (char*)As + 4096 + off);
    gll16(Bt + (size_t)(n0 + srow)      * 768 + k0 + scol, (char*)Bs + off);
    gll16(Bt + (size_t)(n0 + 64 + srow) * 768 + k0 + scol, (char*)Bs + 4096 + off);
    __syncthreads();
    short8 av[4], bv[4];
#pragma unroll
    for (int m = 0; m < 4; ++m)
      av[m] = *(const short8*)(As + (wr * 64 + m * 16 + lrow) * 32 + kb * 8);
#pragma unroll
    for (int n = 0; n < 4; ++n)
      bv[n] = *(const short8*)(Bs + (wc * 64 + n * 16 + lrow) * 32 + kb * 8);
#pragma unroll
    for (int m = 0; m < 4; ++m)
#pragma unroll
      for (int n = 0; n < 4; ++n)
        acc[m][n] = __builtin_amdgcn_mfma_f32_16x16x32_bf16(av[m], bv[n], acc[m][n], 0, 0, 0);
    __syncthreads();
  }

  const float qscale = 0.015625f;  // 4096^-0.5
#pragma unroll
  for (int m = 0; m < 4; ++m) {
    const int row_b = m0 + wr * 64 + m * 16 + kb * 4;
#pragma unroll
    for (int n = 0; n < 4; ++n) {
      const int col = n0 + wc * 64 + n * 16 + lrow;
      const int which = col / 768;
      const int c = col - which * 768;
      const int g = c / 48;
      const int d = c - g * 48;
      const float bv2 = bias[col];
      uint16_t* dst = which == 0 ? Qb : (which == 1 ? Kb : Vb);
      const float sc = which == 0 ? qscale : 1.0f;
#pragma unroll
      for (int r = 0; r < 4; ++r) {
        const int row = row_b + r;
        const int b = row >> 12, nn = row & 4095;
        dst[(((size_t)b * 16 + g) * 4096 + nn) * 48 + d] = f2b((acc[m][n][r] + bv2) * sc);
      }
    }
  }
}

// ---------------- logits partial: part[ch][bg][d][e] = sum_{n in chunk} q[n,d]*k[n,e] ----

__global__ __launch_bounds__(256) void logits_partial_kernel(
    const uint16_t* __restrict__ Qb, const uint16_t* __restrict__ Kb,
    float* __restrict__ part) {
  const int bg = blockIdx.x;   // 0..127
  const int ch = blockIdx.y;   // 0..31 (chunks of 128 tokens)
  const int tid = threadIdx.x;
  __shared__ uint16_t qs[128 * 48];
  __shared__ uint16_t ks[128 * 48];
  const size_t base = ((size_t)bg * 4096 + (size_t)ch * 128) * 48;
  const uint4* qg = (const uint4*)(Qb + base);
  const uint4* kg = (const uint4*)(Kb + base);
#pragma unroll
  for (int i = 0; i < 3; ++i) {
    ((uint4*)qs)[tid + 256 * i] = qg[tid + 256 * i];
    ((uint4*)ks)[tid + 256 * i] = kg[tid + 256 * i];
  }
  __syncthreads();
  const int d0 = (tid >> 4) * 3, e0 = (tid & 15) * 3;
  float acc[3][3] = {};
  for (int n = 0; n < 128; ++n) {
    float qv[3], kv[3];
#pragma unroll
    for (int j = 0; j < 3; ++j) {
      qv[j] = b2f(qs[n * 48 + d0 + j]);
      kv[j] = b2f(ks[n * 48 + e0 + j]);
    }
#pragma unroll
    for (int i2 = 0; i2 < 3; ++i2)
#pragma unroll
      for (int j = 0; j < 3; ++j) acc[i2][j] += qv[i2] * kv[j];
  }
  float* dst = part + ((size_t)ch * 128 + bg) * 2304;
#pragma unroll
  for (int i2 = 0; i2 < 3; ++i2)
#pragma unroll
    for (int j = 0; j < 3; ++j) dst[(d0 + i2) * 48 + e0 + j] = acc[i2][j];
}

// ---------------- reduce partials + softmax over e ----------------

__global__ __launch_bounds__(256) void softmax_kernel(const float* __restrict__ part,
                                                      float* __restrict__ attn) {
  const int bg = blockIdx.x;
  const int tid = threadIdx.x;
  __shared__ float l[2304];
  for (int p = tid; p < 2304; p += 256) {
    float s = 0.f;
    for (int chk = 0; chk < 32; ++chk) s += part[((size_t)chk * 128 + bg) * 2304 + p];
    l[p] = s;
  }
  __syncthreads();
  if (tid < 48) {
    const int d = tid;
    float m = -1e30f;
    for (int e = 0; e < 48; ++e) m = fmaxf(m, l[d * 48 + e]);
    float s = 0.f;
    for (int e = 0; e < 48; ++e) s += expf(l[d * 48 + e] - m);
    const float inv = 1.0f / s;
    for (int e = 0; e < 48; ++e)
      attn[(size_t)bg * 2304 + d * 48 + e] = expf(l[d * 48 + e] - m) * inv;
  }
}

// ---------------- block-diag: ao[b][n][g*48+d] = sum_e attn[bg][d][e] * v[bg][n][e] ------
// MFMA: A = V chunk [128 x 48(pad 64)], B[e][d] = attn[d][e] -> LDS Bs[d][e] row-major pad 64

__global__ __launch_bounds__(256) void blockdiag_kernel(const uint16_t* __restrict__ Vb,
                                                        const float* __restrict__ attn,
                                                        uint16_t* __restrict__ ao) {
  const int bg = blockIdx.x, ch = blockIdx.y;
  const int b = bg >> 4, g = bg & 15;
  const int tid = threadIdx.x;
  __shared__ uint16_t vs[128 * 64];
  __shared__ uint16_t as2[48 * 64];
  const size_t vbase = ((size_t)bg * 4096 + (size_t)ch * 128) * 48;
  for (int i = tid; i < 128 * 64; i += 256) {
    int n = i >> 6, e = i & 63;
    vs[i] = (e < 48) ? Vb[vbase + n * 48 + e] : (uint16_t)0;
  }
  const float* ab = attn + (size_t)bg * 2304;
  for (int i = tid; i < 48 * 64; i += 256) {
    int d = i >> 6, e = i & 63;
    as2[i] = (e < 48) ? f2b(ab[d * 48 + e]) : (uint16_t)0;
  }
  __syncthreads();
  const int lane = tid & 63, w = tid >> 6;
  const int lrow = lane & 15, kb = lane >> 4;
  f32x4 acc[2][3] = {};
#pragma unroll
  for (int ksb = 0; ksb < 2; ++ksb) {
    short8 a[2], bb[3];
#pragma unroll
    for (int i = 0; i < 2; ++i)
      a[i] = *(const short8*)(vs + (w * 32 + i * 16 + lrow) * 64 + ksb * 32 + kb * 8);
#pragma unroll
    for (int c = 0; c < 3; ++c)
      bb[c] = *(const short8*)(as2 + (c * 16 + lrow) * 64 + ksb * 32 + kb * 8);
#pragma unroll
    for (int i = 0; i < 2; ++i)
#pragma unroll
      for (int c = 0; c < 3; ++c)
        acc[i][c] = __builtin_amdgcn_mfma_f32_16x16x32_bf16(a[i], bb[c], acc[i][c], 0, 0, 0);
  }
#pragma unroll
  for (int i = 0; i < 2; ++i)
#pragma unroll
    for (int c = 0; c < 3; ++c)
#pragma unroll
      for (int r = 0; r < 4; ++r) {
        const int nl = w * 32 + i * 16 + kb * 4 + r;
        const int dcol = c * 16 + lrow;
        const size_t row = (size_t)b * 4096 + (size_t)ch * 128 + nl;
        ao[row * 768 + g * 48 + dcol] = f2b(acc[i][c][r]);
      }
}

// ---------------- proj GEMM (128x128 tile) ----------------
// A = ao [32768][768] bf16, Bt = w_projT [768][768] bf16 -> out f32 + b_proj

__global__ __launch_bounds__(256, 2) void gemm_proj_kernel(
    const uint16_t* __restrict__ A, const uint16_t* __restrict__ Bt,
    const float* __restrict__ bias, float* __restrict__ out) {
  __shared__ uint16_t As[128 * 32];
  __shared__ uint16_t Bs[128 * 32];
  const int tid = threadIdx.x;
  const int m0 = blockIdx.x * 128;
  const int n0 = blockIdx.y * 128;
  const int lane = tid & 63, wid = tid >> 6;
  const int wr = wid >> 1, wc = wid & 1;
  const int lrow = lane & 15, kb = lane >> 4;

  const int off  = tid * 16;
  const int srow = off >> 6;
  const int scol = (off & 63) >> 1;

  f32x4 acc[4][4] = {};

  for (int k0 = 0; k0 < 768; k0 += 32) {
    gll16(A  + (size_t)(m0 + srow)      * 768 + k0 + scol, (char*)As + off);
    gll16(A  + (size_t)(m0 + 64 + srow) * 768 + k0 + scol, (char*)As + 4096 + off);
    gll16(Bt + (size_t)(n0 + srow)      * 768 + k0 + scol, (char*)Bs + off);
    gll16(Bt + (size_t)(n0 + 64 + srow) * 768 + k0 + scol, (char*)Bs + 4096 + off);
    __syncthreads();
    short8 av[4], bv[4];
#pragma unroll
    for (int m = 0; m < 4; ++m)
      av[m] = *(const short8*)(As + (wr * 64 + m * 16 + lrow) * 32 + kb * 8);
#pragma unroll
    for (int n = 0; n < 4; ++n)
      bv[n] = *(const short8*)(Bs + (wc * 64 + n * 16 + lrow) * 32 + kb * 8);
#pragma unroll
    for (int m = 0; m < 4; ++m)
#pragma unroll
      for (int n = 0; n < 4; ++n)
        acc[m][n] = __builtin_amdgcn_mfma_f32_16x16x32_bf16(av[m], bv[n], acc[m][n], 0, 0, 0);
    __syncthreads();
  }

#pragma unroll
  for (int m = 0; m < 4; ++m) {
    const int row_b = m0 + wr * 64 + m * 16 + kb * 4;
#pragma unroll
    for (int n = 0; n < 4; ++n) {
      const int col = n0 + wc * 64 + n * 16 + lrow;
      const float bv2 = bias[col];
#pragma unroll
      for (int r = 0; r < 4; ++r)
        out[(size_t)(row_b + r) * 768 + col] = acc[m][n][r] + bv2;
    }
  }
}

// ---------------- launcher ----------------

extern "C" void kernel_launch(void* const* d_in, const int* in_sizes, int n_in,
                              void* d_out, int out_size, void* d_ws, size_t ws_size,
                              hipStream_t stream) {
  const float* x      = (const float*)d_in[0];
  const float* w_qkv  = (const float*)d_in[1];
  const float* b_qkv  = (const float*)d_in[2];
  const float* w_proj = (const float*)d_in[3];
  const float* b_proj = (const float*)d_in[4];
  float* out = (float*)d_out;

  char* w = (char*)d_ws;
  uint16_t* xb  = (uint16_t*)w; w += (size_t)32768 * 768 * 2;      // 50.3 MB (reused as ao)
  uint16_t* wqT = (uint16_t*)w; w += (size_t)2304 * 768 * 2;       // 3.5 MB
  uint16_t* wpT = (uint16_t*)w; w += (size_t)768 * 768 * 2;        // 1.2 MB
  uint16_t* Qb  = (uint16_t*)w; w += (size_t)128 * 4096 * 48 * 2;  // 50.3 MB
  uint16_t* Kb  = (uint16_t*)w; w += (size_t)128 * 4096 * 48 * 2;  // 50.3 MB
  uint16_t* Vb  = (uint16_t*)w; w += (size_t)128 * 4096 * 48 * 2;  // 50.3 MB
  float* part   = (float*)w;    w += (size_t)32 * 128 * 2304 * 4;  // 37.7 MB
  float* attn   = (float*)w;    w += (size_t)128 * 2304 * 4;       // 1.2 MB
  uint16_t* ao  = xb;  // x_bf16 is dead after gemm_qkv; alias to save workspace

  cast_x_kernel<<<24576, 256, 0, stream>>>(x, xb, 6291456);
  transpose_cast_kernel<<<6912, 256, 0, stream>>>(w_qkv, wqT, 768, 2304);
  transpose_cast_kernel<<<2304, 256, 0, stream>>>(w_proj, wpT, 768, 768);
  gemm_qkv_kernel<<<dim3(256, 18), 256, 0, stream>>>(xb, wqT, b_qkv, Qb, Kb, Vb);
  logits_partial_kernel<<<dim3(128, 32), 256, 0, stream>>>(Qb, Kb, part);
  softmax_kernel<<<128, 256, 0, stream>>>(part, attn);
  blockdiag_kernel<<<dim3(128, 32), 256, 0, stream>>>(Vb, attn, ao);
  gemm_proj_kernel<<<dim3(256, 6), 256, 0, stream>>>(ao, wpT, b_proj, out);
}

// Round 2
// 370.990 us; speedup vs baseline: 2.1788x; 2.1788x over previous
//
#include <hip/hip_runtime.h>
#include <stdint.h>

// Problem constants: B=8, N=4096, C=768, G=16, D=48
// qkv GEMM: M=32768, N=2304, K=768 ; proj GEMM: M=32768, N=768, K=768

using short8 = __attribute__((__ext_vector_type__(8))) short;
using f32x4  = __attribute__((__ext_vector_type__(4))) float;

typedef const void __attribute__((address_space(1))) gv_t;
typedef void __attribute__((address_space(3))) lv_t;

__device__ __forceinline__ void gll16(const void* g, void* l) {
  __builtin_amdgcn_global_load_lds((gv_t*)g, (lv_t*)l, 16, 0, 0);
}

__device__ __forceinline__ uint16_t f2b(float f) {
  uint32_t x = __float_as_uint(f);
  uint32_t r = (x + 0x7fffu + ((x >> 16) & 1u)) >> 16;  // RNE
  return (uint16_t)r;
}
__device__ __forceinline__ float b2f(uint16_t u) {
  return __uint_as_float(((uint32_t)u) << 16);
}

// ---------------- cast / transpose helpers ----------------

__global__ __launch_bounds__(256) void cast_x_kernel(const float* __restrict__ x,
                                                     uint16_t* __restrict__ xb, int n4) {
  int i = blockIdx.x * 256 + threadIdx.x;
  if (i >= n4) return;
  f32x4 v = ((const f32x4*)x)[i];
  union { uint16_t u[4]; uint64_t q; } o;
  o.u[0] = f2b(v[0]); o.u[1] = f2b(v[1]); o.u[2] = f2b(v[2]); o.u[3] = f2b(v[3]);
  ((uint64_t*)xb)[i] = o.q;
}

// wt[n*K + k] = (bf16) w[k*N + n]
__global__ __launch_bounds__(256) void transpose_cast_kernel(const float* __restrict__ w,
                                                             uint16_t* __restrict__ wt,
                                                             int K, int N) {
  int i = blockIdx.x * 256 + threadIdx.x;
  if (i >= N * K) return;
  int n = i / K, k = i - n * K;
  wt[i] = f2b(w[(size_t)k * N + n]);
}

// ---------------- QKV GEMM (128x128 tile, bf16 MFMA) ----------------
// A [32768][768] bf16, Bt [2304][768] bf16 (w_qkv transposed)
// Q/K tiles: swapped-operand MFMA -> transposed output -> Qt/Kt [bg][48][4096]
// V tiles: normal -> Vb [bg][4096][48]

__global__ __launch_bounds__(256, 2) void gemm_qkv_kernel(
    const uint16_t* __restrict__ A, const uint16_t* __restrict__ Bt,
    const float* __restrict__ bias,
    uint16_t* __restrict__ Qt, uint16_t* __restrict__ Kt, uint16_t* __restrict__ Vb) {
  __shared__ uint16_t As[128 * 32];
  __shared__ uint16_t Bs[128 * 32];
  const int tid = threadIdx.x;
  const int m0 = blockIdx.x * 128;
  const int n0 = blockIdx.y * 128;
  const int lane = tid & 63, wid = tid >> 6;
  const int wr = wid >> 1, wc = wid & 1;
  const int lrow = lane & 15, kb = lane >> 4;
  const int which = n0 / 768;              // 0=Q 1=K 2=V (uniform per block)
  const bool sw = (which < 2);

  const int off  = tid * 16;          // staging byte offset within 4KB half
  const int srow = off >> 6;          // 64B (=32 bf16) per LDS row
  const int scol = (off & 63) >> 1;   // element col (multiple of 8)

  f32x4 acc[4][4] = {};

  for (int k0 = 0; k0 < 768; k0 += 32) {
    gll16(A  + (size_t)(m0 + srow)      * 768 + k0 + scol, (char*)As + off);
    gll16(A  + (size_t)(m0 + 64 + srow) * 768 + k0 + scol, (char*)As + 4096 + off);
    gll16(Bt + (size_t)(n0 + srow)      * 768 + k0 + scol, (char*)Bs + off);
    gll16(Bt + (size_t)(n0 + 64 + srow) * 768 + k0 + scol, (char*)Bs + 4096 + off);
    __syncthreads();
    short8 av[4], bv[4];
#pragma unroll
    for (int m = 0; m < 4; ++m)
      av[m] = *(const short8*)(As + (wr * 64 + m * 16 + lrow) * 32 + kb * 8);
#pragma unroll
    for (int n = 0; n < 4; ++n)
      bv[n] = *(const short8*)(Bs + (wc * 64 + n * 16 + lrow) * 32 + kb * 8);
    if (sw) {
#pragma unroll
      for (int m = 0; m < 4; ++m)
#pragma unroll
        for (int n = 0; n < 4; ++n)
          acc[m][n] = __builtin_amdgcn_mfma_f32_16x16x32_bf16(bv[n], av[m], acc[m][n], 0, 0, 0);
    } else {
#pragma unroll
      for (int m = 0; m < 4; ++m)
#pragma unroll
        for (int n = 0; n < 4; ++n)
          acc[m][n] = __builtin_amdgcn_mfma_f32_16x16x32_bf16(av[m], bv[n], acc[m][n], 0, 0, 0);
    }
    __syncthreads();
  }

  const float qscale = 0.015625f;  // 4096^-0.5
  if (sw) {
    // transposed fragments: row of frag = weight channel, col of frag = token
    uint16_t* dst = (which == 0) ? Qt : Kt;
    const float sc = (which == 0) ? qscale : 1.0f;
#pragma unroll
    for (int m = 0; m < 4; ++m) {
      const int token = m0 + wr * 64 + m * 16 + lrow;   // per-lane, 16 consecutive
      const int b = token >> 12, nn = token & 4095;
#pragma unroll
      for (int n = 0; n < 4; ++n) {
        const int c0 = n0 - which * 768 + wc * 64 + n * 16 + kb * 4;
#pragma unroll
        for (int r = 0; r < 4; ++r) {
          const int chan = c0 + r;
          const int g = chan / 48;
          const int d = chan - g * 48;
          const float bvv = bias[n0 + wc * 64 + n * 16 + kb * 4 + r];
          dst[(((size_t)b * 16 + g) * 48 + d) * 4096 + nn] = f2b((acc[m][n][r] + bvv) * sc);
        }
      }
    }
  } else {
#pragma unroll
    for (int m = 0; m < 4; ++m) {
      const int row_b = m0 + wr * 64 + m * 16 + kb * 4;
#pragma unroll
      for (int n = 0; n < 4; ++n) {
        const int col = n0 + wc * 64 + n * 16 + lrow;
        const int c = col - 2 * 768;
        const int g = c / 48;
        const int d = c - g * 48;
        const float bv2 = bias[col];
#pragma unroll
        for (int r = 0; r < 4; ++r) {
          const int row = row_b + r;
          const int b = row >> 12, nn = row & 4095;
          Vb[(((size_t)b * 16 + g) * 4096 + nn) * 48 + d] = f2b(acc[m][n][r] + bv2);
        }
      }
    }
  }
}

// ---------------- logits via MFMA over token-K ----------------
// Qt,Kt: [bg][48][4096] bf16.  part[ch][bg][48][48] f32, ch in 0..7 (512 tokens each)
// C[d][e] = sum_n Qt[d][n] * Kt[e][n]; A-frag = Qt rows, B-frag = Kt rows (same layout).

__global__ __launch_bounds__(256) void logits_mfma_kernel(
    const uint16_t* __restrict__ Qt, const uint16_t* __restrict__ Kt,
    float* __restrict__ part) {
  const int bg = blockIdx.x;     // 0..127
  const int ch = blockIdx.y;     // 0..7
  const int tid = threadIdx.x;
  const int lane = tid & 63, w = tid >> 6;
  const int lrow = lane & 15, kb = lane >> 4;

  const size_t qbase = (size_t)bg * 48 * 4096;
  const int tok0 = ch * 512 + w * 128;

  f32x4 acc[3][3] = {};
#pragma unroll
  for (int s = 0; s < 4; ++s) {
    const int tok = tok0 + s * 32 + kb * 8;
    short8 av[3], bvv[3];
#pragma unroll
    for (int dm = 0; dm < 3; ++dm) {
      av[dm]  = *(const short8*)(Qt + qbase + (size_t)(dm * 16 + lrow) * 4096 + tok);
      bvv[dm] = *(const short8*)(Kt + qbase + (size_t)(dm * 16 + lrow) * 4096 + tok);
    }
#pragma unroll
    for (int dm = 0; dm < 3; ++dm)
#pragma unroll
      for (int em = 0; em < 3; ++em)
        acc[dm][em] = __builtin_amdgcn_mfma_f32_16x16x32_bf16(av[dm], bvv[em], acc[dm][em], 0, 0, 0);
  }

  // block reduce over 4 waves
  __shared__ float red[4][2304];
#pragma unroll
  for (int dm = 0; dm < 3; ++dm)
#pragma unroll
    for (int em = 0; em < 3; ++em)
#pragma unroll
      for (int r = 0; r < 4; ++r) {
        const int d = dm * 16 + kb * 4 + r;
        const int e = em * 16 + lrow;
        red[w][d * 48 + e] = acc[dm][em][r];
      }
  __syncthreads();
  float* dst = part + ((size_t)ch * 128 + bg) * 2304;
  for (int i = tid; i < 2304; i += 256)
    dst[i] = red[0][i] + red[1][i] + red[2][i] + red[3][i];
}

// ---------------- reduce partials + softmax over e ----------------

__global__ __launch_bounds__(256) void softmax_kernel(const float* __restrict__ part,
                                                      float* __restrict__ attn) {
  const int bg = blockIdx.x;
  const int tid = threadIdx.x;
  __shared__ float l[2304];
  for (int p = tid; p < 2304; p += 256) {
    float s = 0.f;
    for (int chk = 0; chk < 8; ++chk) s += part[((size_t)chk * 128 + bg) * 2304 + p];
    l[p] = s;
  }
  __syncthreads();
  if (tid < 48) {
    const int d = tid;
    float m = -1e30f;
    for (int e = 0; e < 48; ++e) m = fmaxf(m, l[d * 48 + e]);
    float s = 0.f;
    for (int e = 0; e < 48; ++e) s += expf(l[d * 48 + e] - m);
    const float inv = 1.0f / s;
    for (int e = 0; e < 48; ++e)
      attn[(size_t)bg * 2304 + d * 48 + e] = expf(l[d * 48 + e] - m) * inv;
  }
}

// ---------------- block-diag: ao[b][n][g*48+d] = sum_e attn[bg][d][e] * v[bg][n][e] ------

__global__ __launch_bounds__(256) void blockdiag_kernel(const uint16_t* __restrict__ Vb,
                                                        const float* __restrict__ attn,
                                                        uint16_t* __restrict__ ao) {
  const int bg = blockIdx.x, ch = blockIdx.y;
  const int b = bg >> 4, g = bg & 15;
  const int tid = threadIdx.x;
  __shared__ uint16_t vs[128 * 64];
  __shared__ uint16_t as2[48 * 64];
  const size_t vbase = ((size_t)bg * 4096 + (size_t)ch * 128) * 48;
  for (int i = tid; i < 128 * 64; i += 256) {
    int n = i >> 6, e = i & 63;
    vs[i] = (e < 48) ? Vb[vbase + n * 48 + e] : (uint16_t)0;
  }
  const float* ab = attn + (size_t)bg * 2304;
  for (int i = tid; i < 48 * 64; i += 256) {
    int d = i >> 6, e = i & 63;
    as2[i] = (e < 48) ? f2b(ab[d * 48 + e]) : (uint16_t)0;
  }
  __syncthreads();
  const int lane = tid & 63, w = tid >> 6;
  const int lrow = lane & 15, kb = lane >> 4;
  f32x4 acc[2][3] = {};
#pragma unroll
  for (int ksb = 0; ksb < 2; ++ksb) {
    short8 a[2], bb[3];
#pragma unroll
    for (int i = 0; i < 2; ++i)
      a[i] = *(const short8*)(vs + (w * 32 + i * 16 + lrow) * 64 + ksb * 32 + kb * 8);
#pragma unroll
    for (int c = 0; c < 3; ++c)
      bb[c] = *(const short8*)(as2 + (c * 16 + lrow) * 64 + ksb * 32 + kb * 8);
#pragma unroll
    for (int i = 0; i < 2; ++i)
#pragma unroll
      for (int c = 0; c < 3; ++c)
        acc[i][c] = __builtin_amdgcn_mfma_f32_16x16x32_bf16(a[i], bb[c], acc[i][c], 0, 0, 0);
  }
#pragma unroll
  for (int i = 0; i < 2; ++i)
#pragma unroll
    for (int c = 0; c < 3; ++c)
#pragma unroll
      for (int r = 0; r < 4; ++r) {
        const int nl = w * 32 + i * 16 + kb * 4 + r;
        const int dcol = c * 16 + lrow;
        const size_t row = (size_t)b * 4096 + (size_t)ch * 128 + nl;
        ao[row * 768 + g * 48 + dcol] = f2b(acc[i][c][r]);
      }
}

// ---------------- proj GEMM (128x128 tile) ----------------

__global__ __launch_bounds__(256, 2) void gemm_proj_kernel(
    const uint16_t* __restrict__ A, const uint16_t* __restrict__ Bt,
    const float* __restrict__ bias, float* __restrict__ out) {
  __shared__ uint16_t As[128 * 32];
  __shared__ uint16_t Bs[128 * 32];
  const int tid = threadIdx.x;
  const int m0 = blockIdx.x * 128;
  const int n0 = blockIdx.y * 128;
  const int lane = tid & 63, wid = tid >> 6;
  const int wr = wid >> 1, wc = wid & 1;
  const int lrow = lane & 15, kb = lane >> 4;

  const int off  = tid * 16;
  const int srow = off >> 6;
  const int scol = (off & 63) >> 1;

  f32x4 acc[4][4] = {};

  for (int k0 = 0; k0 < 768; k0 += 32) {
    gll16(A  + (size_t)(m0 + srow)      * 768 + k0 + scol, (char*)As + off);
    gll16(A  + (size_t)(m0 + 64 + srow) * 768 + k0 + scol, (char*)As + 4096 + off);
    gll16(Bt + (size_t)(n0 + srow)      * 768 + k0 + scol, (char*)Bs + off);
    gll16(Bt + (size_t)(n0 + 64 + srow) * 768 + k0 + scol, (char*)Bs + 4096 + off);
    __syncthreads();
    short8 av[4], bv[4];
#pragma unroll
    for (int m = 0; m < 4; ++m)
      av[m] = *(const short8*)(As + (wr * 64 + m * 16 + lrow) * 32 + kb * 8);
#pragma unroll
    for (int n = 0; n < 4; ++n)
      bv[n] = *(const short8*)(Bs + (wc * 64 + n * 16 + lrow) * 32 + kb * 8);
#pragma unroll
    for (int m = 0; m < 4; ++m)
#pragma unroll
      for (int n = 0; n < 4; ++n)
        acc[m][n] = __builtin_amdgcn_mfma_f32_16x16x32_bf16(av[m], bv[n], acc[m][n], 0, 0, 0);
    __syncthreads();
  }

#pragma unroll
  for (int m = 0; m < 4; ++m) {
    const int row_b = m0 + wr * 64 + m * 16 + kb * 4;
#pragma unroll
    for (int n = 0; n < 4; ++n) {
      const int col = n0 + wc * 64 + n * 16 + lrow;
      const float bv2 = bias[col];
#pragma unroll
      for (int r = 0; r < 4; ++r)
        out[(size_t)(row_b + r) * 768 + col] = acc[m][n][r] + bv2;
    }
  }
}

// ---------------- launcher ----------------

extern "C" void kernel_launch(void* const* d_in, const int* in_sizes, int n_in,
                              void* d_out, int out_size, void* d_ws, size_t ws_size,
                              hipStream_t stream) {
  const float* x      = (const float*)d_in[0];
  const float* w_qkv  = (const float*)d_in[1];
  const float* b_qkv  = (const float*)d_in[2];
  const float* w_proj = (const float*)d_in[3];
  const float* b_proj = (const float*)d_in[4];
  float* out = (float*)d_out;

  char* w = (char*)d_ws;
  uint16_t* xb  = (uint16_t*)w; w += (size_t)32768 * 768 * 2;      // 50.3 MB (reused as ao)
  uint16_t* wqT = (uint16_t*)w; w += (size_t)2304 * 768 * 2;       // 3.5 MB
  uint16_t* wpT = (uint16_t*)w; w += (size_t)768 * 768 * 2;        // 1.2 MB
  uint16_t* Qt  = (uint16_t*)w; w += (size_t)128 * 48 * 4096 * 2;  // 50.3 MB
  uint16_t* Kt  = (uint16_t*)w; w += (size_t)128 * 48 * 4096 * 2;  // 50.3 MB
  uint16_t* Vb  = (uint16_t*)w; w += (size_t)128 * 4096 * 48 * 2;  // 50.3 MB
  float* part   = (float*)w;    w += (size_t)8 * 128 * 2304 * 4;   // 9.4 MB
  float* attn   = (float*)w;    w += (size_t)128 * 2304 * 4;       // 1.2 MB
  uint16_t* ao  = xb;  // x_bf16 is dead after gemm_qkv; alias to save workspace

  cast_x_kernel<<<24576, 256, 0, stream>>>(x, xb, 6291456);
  transpose_cast_kernel<<<6912, 256, 0, stream>>>(w_qkv, wqT, 768, 2304);
  transpose_cast_kernel<<<2304, 256, 0, stream>>>(w_proj, wpT, 768, 768);
  gemm_qkv_kernel<<<dim3(256, 18), 256, 0, stream>>>(xb, wqT, b_qkv, Qt, Kt, Vb);
  logits_mfma_kernel<<<dim3(128, 8), 256, 0, stream>>>(Qt, Kt, part);
  softmax_kernel<<<128, 256, 0, stream>>>(part, attn);
  blockdiag_kernel<<<dim3(128, 32), 256, 0, stream>>>(Vb, attn, ao);
  gemm_proj_kernel<<<dim3(256, 6), 256, 0, stream>>>(ao, wpT, b_proj, out);
}